// Round 5
// baseline (57.213 us; speedup 1.0000x reference)
//
#include <hip/hip_runtime.h>
#include <hip/hip_bf16.h>
#include <math.h>

#define NPIX   4096
#define STEPF  (6.0f/63.0f)
#define SCALE  0.35355339059327373f  // 1/sqrt(8)

#define OFF_PT 0
#define OFF_PB 4096
#define OFF_Q  65536
#define OFF_K  (OFF_Q + 1048576)
#define OFF_V  (OFF_K + 1048576)

// ---------------------------------------------------------------------------
// K_A: merged positional-FFN + Q/K/V projection, 256 blocks exactly (1/CU).
//  blocks [0,192): qkv — 64 px-blocks x 3 matrices, 4 px/thread
//  blocks [192,256): pos FFN -> PT[49][8], PB[4096][8]; 65 entries/block
// ---------------------------------------------------------------------------
__global__ __launch_bounds__(256, 2) void pos_qkv_kernel(
    const float* __restrict__ x,
    const float* __restrict__ wq, const float* __restrict__ bq,
    const float* __restrict__ wk, const float* __restrict__ bk,
    const float* __restrict__ wv, const float* __restrict__ bv,
    const float* __restrict__ pw1, const float* __restrict__ pb1,
    const float* __restrict__ pw2, const float* __restrict__ pb2,
    float* __restrict__ Qo, float* __restrict__ Ko, float* __restrict__ Vo,
    float* __restrict__ PT, float* __restrict__ PB)
{
    __shared__ __align__(16) float smem[5632];
    int tid = threadIdx.x;
    int bid = blockIdx.x;

    if (bid < 192) {
        // ---------------- QKV projection ----------------
        int mat = bid >> 6;
        const float* W; const float* bias; float* out;
        if (mat == 0)      { W = wq; bias = bq; out = Qo; }
        else if (mat == 1) { W = wk; bias = bk; out = Ko; }
        else               { W = wv; bias = bv; out = Vo; }

        float* s_W = smem;
        float* s_b = smem + 4096;
        {
            const float4* W4 = (const float4*)W;
            float4* s4 = (float4*)s_W;
            #pragma unroll
            for (int q = 0; q < 4; ++q) s4[tid + q * 256] = W4[tid + q * 256];
        }
        if (tid < 64) s_b[tid] = bias[tid];
        __syncthreads();

        int jg = tid & 3;            // 16-col output group
        int pl = tid >> 2;           // 0..63 -> 4 consecutive pixels each
        int pxblk = bid & 63;
        int g0 = pxblk << 8;         // 256 px per block, never straddles batch
        int b  = g0 >> 12;
        int pp = g0 & 4095;
        const float* xb = x + ((size_t)b << 18) + pp + (pl << 2);

        float acc[4][16];
        #pragma unroll
        for (int jj = 0; jj < 16; ++jj) {
            float bv_ = s_b[(jg << 4) + jj];
            acc[0][jj] = bv_; acc[1][jj] = bv_; acc[2][jj] = bv_; acc[3][jj] = bv_;
        }

        #pragma unroll 2
        for (int c = 0; c < 64; ++c) {
            float4 xv = *(const float4*)(xb + ((size_t)c << 12));
            const float* wr = &s_W[(c << 6) + (jg << 4)];
            const float4 w0 = *(const float4*)(wr + 0);
            const float4 w1v = *(const float4*)(wr + 4);
            const float4 w2v = *(const float4*)(wr + 8);
            const float4 w3v = *(const float4*)(wr + 12);
            float xs[4] = {xv.x, xv.y, xv.z, xv.w};
            #pragma unroll
            for (int e = 0; e < 4; ++e) {
                float xe = xs[e];
                acc[e][0]  = fmaf(xe, w0.x,  acc[e][0]);
                acc[e][1]  = fmaf(xe, w0.y,  acc[e][1]);
                acc[e][2]  = fmaf(xe, w0.z,  acc[e][2]);
                acc[e][3]  = fmaf(xe, w0.w,  acc[e][3]);
                acc[e][4]  = fmaf(xe, w1v.x, acc[e][4]);
                acc[e][5]  = fmaf(xe, w1v.y, acc[e][5]);
                acc[e][6]  = fmaf(xe, w1v.z, acc[e][6]);
                acc[e][7]  = fmaf(xe, w1v.w, acc[e][7]);
                acc[e][8]  = fmaf(xe, w2v.x, acc[e][8]);
                acc[e][9]  = fmaf(xe, w2v.y, acc[e][9]);
                acc[e][10] = fmaf(xe, w2v.z, acc[e][10]);
                acc[e][11] = fmaf(xe, w2v.w, acc[e][11]);
                acc[e][12] = fmaf(xe, w3v.x, acc[e][12]);
                acc[e][13] = fmaf(xe, w3v.y, acc[e][13]);
                acc[e][14] = fmaf(xe, w3v.z, acc[e][14]);
                acc[e][15] = fmaf(xe, w3v.w, acc[e][15]);
            }
        }

        #pragma unroll
        for (int e = 0; e < 4; ++e) {
            float* op = out + (size_t)(g0 + (pl << 2) + e) * 64 + (jg << 4);
            *(float4*)(op + 0)  = make_float4(acc[e][0],  acc[e][1],  acc[e][2],  acc[e][3]);
            *(float4*)(op + 4)  = make_float4(acc[e][4],  acc[e][5],  acc[e][6],  acc[e][7]);
            *(float4*)(op + 8)  = make_float4(acc[e][8],  acc[e][9],  acc[e][10], acc[e][11]);
            *(float4*)(op + 12) = make_float4(acc[e][12], acc[e][13], acc[e][14], acc[e][15]);
        }
    } else {
        // ---------------- positional FFN ----------------
        float* s_w1 = smem;          // 1024
        float* s_b1 = smem + 1024;   // 512
        float* s_w2 = smem + 1536;   // 4096
        {
            float4* s4 = (float4*)smem;
            s4[tid] = ((const float4*)pw1)[tid];
            if (tid < 128) ((float4*)s_b1)[tid] = ((const float4*)pb1)[tid];
            float4* w24 = (float4*)s_w2;
            #pragma unroll
            for (int q = 0; q < 4; ++q) w24[tid + q * 256] = ((const float4*)pw2)[tid + q * 256];
        }
        __syncthreads();

        int base = (bid - 192) * 65;           // 65 entries per block
        int lg = tid & 7;
        for (int el = tid >> 3; el < 65; el += 32) {
            int e = base + el;
            if (e >= 49 + NPIX) break;

            float r0, r1;
            if (e < 49) {
                int di = e / 7, dj = e % 7;
                r0 = (float)(di - 3) * STEPF;
                r1 = (float)(dj - 3) * STEPF;
            } else {
                int pq = e - 49;
                r0 = 3.0f - (float)(pq >> 6) * STEPF;
                r1 = 3.0f - (float)(pq & 63) * STEPF;
            }

            float acc[8] = {0.f,0.f,0.f,0.f,0.f,0.f,0.f,0.f};
            #pragma unroll 8
            for (int kk = 0; kk < 64; ++kk) {
                int k = (kk << 3) + lg;
                float hv = fmaf(r0, s_w1[k], fmaf(r1, s_w1[512 + k], s_b1[k]));
                hv = fmaxf(hv, 0.0f);
                const float4 wa = *(const float4*)&s_w2[k * 8];
                const float4 wb = *(const float4*)&s_w2[k * 8 + 4];
                acc[0] = fmaf(hv, wa.x, acc[0]);
                acc[1] = fmaf(hv, wa.y, acc[1]);
                acc[2] = fmaf(hv, wa.z, acc[2]);
                acc[3] = fmaf(hv, wa.w, acc[3]);
                acc[4] = fmaf(hv, wb.x, acc[4]);
                acc[5] = fmaf(hv, wb.y, acc[5]);
                acc[6] = fmaf(hv, wb.z, acc[6]);
                acc[7] = fmaf(hv, wb.w, acc[7]);
            }
            #pragma unroll
            for (int m = 1; m < 8; m <<= 1) {
                #pragma unroll
                for (int jx = 0; jx < 8; ++jx) acc[jx] += __shfl_xor(acc[jx], m);
            }
            float v = acc[lg] + pb2[lg];
            if (e < 49) PT[e * 8 + lg] = v;
            else        PB[(e - 49) * 8 + lg] = v;
        }
    }
}

// ---------------------------------------------------------------------------
// K_B: neighborhood attention, LDS-staged K/V halo, fused output projection.
// Block = 32-px row chunk x 8 heads (256 thr). LDS: KV tile [7][38][68]
// reused for K then V; PT in VGPRs; WO read from global (broadcast, L1-hot).
// 4 barriers; 81,312 B LDS -> 2 blocks/CU.
// ---------------------------------------------------------------------------
__global__ __launch_bounds__(256, 2) void attn_fused_kernel(
    const float* __restrict__ Q, const float* __restrict__ K,
    const float* __restrict__ V, const float* __restrict__ PT,
    const float* __restrict__ PB, const float* __restrict__ WO,
    const float* __restrict__ bO, float* __restrict__ out)
{
    __shared__ __align__(16) float s_KV[7 * 38 * 68];   // 72,352 B
    __shared__ __align__(16) float s_O[32 * 68];        //  8,704 B
    __shared__ float s_bias[64];

    int tid  = threadIdx.x;
    int bid  = blockIdx.x;
    int b    = bid >> 7;            // 128 blocks per batch
    int pblk = bid & 127;
    int i    = pblk >> 1;
    int j0   = (pblk & 1) << 5;
    int h    = tid & 7;
    int pxl  = tid >> 3;            // 0..31
    int j    = j0 + pxl;
    int p    = (i << 6) + j;

    if (tid < 64) s_bias[tid] = bO[tid];

    // positional tables -> registers
    float pt[49];
    #pragma unroll
    for (int r = 0; r < 49; ++r) pt[r] = PT[(r << 3) + h];
    float pbv = PB[(p << 3) + h];

    const float* qp = Q + ((size_t)((b << 12) + p) << 6) + (h << 3);
    const float4 qa = *(const float4*)qp;
    const float4 qb = *(const float4*)(qp + 4);

    const float* Kb = K + ((size_t)b << 18);
    const float* Vb = V + ((size_t)b << 18);

    // ---- stage K halo: rows i-3..i+3 (clamped), cols j0-3..j0+34 (clamped) ----
    #pragma unroll
    for (int r = 0; r < 7; ++r) {
        int ic = i - 3 + r; ic = ic < 0 ? 0 : (ic > 63 ? 63 : ic);
        const float* rowb = Kb + ((size_t)ic << 12);
        for (int v = tid; v < 608; v += 256) {        // 38 cols * 16 float4
            int cc = v >> 4, q4 = v & 15;
            int jc = j0 - 3 + cc; jc = jc < 0 ? 0 : (jc > 63 ? 63 : jc);
            *(float4*)&s_KV[(r * 38 + cc) * 68 + (q4 << 2)] =
                *(const float4*)(rowb + (jc << 6) + (q4 << 2));
        }
    }
    __syncthreads();

    // ---- score pass ----
    float sc[49];
    float mx = -1e30f;
    #pragma unroll
    for (int di = 0; di < 7; ++di) {
        int i2 = i + di - 3;
        bool iok = (unsigned)i2 < 64u;
        const float* krow = &s_KV[(di * 38 + pxl) * 68 + (h << 3)];
        #pragma unroll
        for (int dj = 0; dj < 7; ++dj) {
            int j2 = j + dj - 3;
            bool ok = iok && ((unsigned)j2 < 64u);
            const float* kp = krow + dj * 68;
            const float4 ka  = *(const float4*)kp;
            const float4 kb2 = *(const float4*)(kp + 4);
            float da = fmaf(qa.y, ka.y, qa.x * ka.x);
            da = fmaf(qa.w, ka.w, fmaf(qa.z, ka.z, da));
            float db = fmaf(qb.y, kb2.y, qb.x * kb2.x);
            db = fmaf(qb.w, kb2.w, fmaf(qb.z, kb2.z, db));
            int r = di * 7 + dj;
            float s = fmaf(da + db, SCALE, pt[r]);
            s = ok ? s : pbv;
            sc[r] = s;
            mx = fmaxf(mx, s);
        }
    }
    __syncthreads();   // all K reads complete before overwrite

    // ---- stage V halo into the same buffer ----
    #pragma unroll
    for (int r = 0; r < 7; ++r) {
        int ic = i - 3 + r; ic = ic < 0 ? 0 : (ic > 63 ? 63 : ic);
        const float* rowb = Vb + ((size_t)ic << 12);
        for (int v = tid; v < 608; v += 256) {
            int cc = v >> 4, q4 = v & 15;
            int jc = j0 - 3 + cc; jc = jc < 0 ? 0 : (jc > 63 ? 63 : jc);
            *(float4*)&s_KV[(r * 38 + cc) * 68 + (q4 << 2)] =
                *(const float4*)(rowb + (jc << 6) + (q4 << 2));
        }
    }
    __syncthreads();

    // ---- softmax + PV ----
    float sum = 0.0f;
    float o0=0.f,o1=0.f,o2=0.f,o3=0.f,o4=0.f,o5=0.f,o6=0.f,o7=0.f;
    #pragma unroll
    for (int di = 0; di < 7; ++di) {
        int i2 = i + di - 3;
        bool iok = (unsigned)i2 < 64u;
        const float* vrow = &s_KV[(di * 38 + pxl) * 68 + (h << 3)];
        #pragma unroll
        for (int dj = 0; dj < 7; ++dj) {
            int j2 = j + dj - 3;
            bool ok = iok && ((unsigned)j2 < 64u);
            int r = di * 7 + dj;
            float e = __expf(sc[r] - mx);
            sum += e;
            float ew = ok ? e : 0.0f;
            const float* vp = vrow + dj * 68;
            const float4 va  = *(const float4*)vp;
            const float4 vb2 = *(const float4*)(vp + 4);
            o0 = fmaf(ew, va.x, o0); o1 = fmaf(ew, va.y, o1);
            o2 = fmaf(ew, va.z, o2); o3 = fmaf(ew, va.w, o3);
            o4 = fmaf(ew, vb2.x, o4); o5 = fmaf(ew, vb2.y, o5);
            o6 = fmaf(ew, vb2.z, o6); o7 = fmaf(ew, vb2.w, o7);
        }
    }
    float inv = 1.0f / sum;
    {
        float* so = &s_O[pxl * 68 + (h << 3)];
        *(float4*)(so + 0) = make_float4(o0 * inv, o1 * inv, o2 * inv, o3 * inv);
        *(float4*)(so + 4) = make_float4(o4 * inv, o5 * inv, o6 * inv, o7 * inv);
    }
    __syncthreads();   // s_O complete

    // ---- epilogue: out[b, ch, p] = bias[ch] + sum_c s_O[p][c] * WO[c][ch]
    //      WO read directly from global: uniform per cg-group -> 1 line/instr,
    //      L1-resident after first touch.
    int pl2 = tid & 31;
    int cg  = tid >> 5;           // 8 output channels per thread
    float acc[8];
    #pragma unroll
    for (int k = 0; k < 8; ++k) acc[k] = s_bias[(cg << 3) + k];

    #pragma unroll 4
    for (int c4 = 0; c4 < 16; ++c4) {
        float4 xv = *(const float4*)&s_O[pl2 * 68 + (c4 << 2)];
        float xs[4] = {xv.x, xv.y, xv.z, xv.w};
        #pragma unroll
        for (int e = 0; e < 4; ++e) {
            int c = (c4 << 2) + e;
            const float* wr = WO + (c << 6) + (cg << 3);
            const float4 wa = *(const float4*)wr;
            const float4 wb = *(const float4*)(wr + 4);
            float xe = xs[e];
            acc[0] = fmaf(xe, wa.x, acc[0]); acc[1] = fmaf(xe, wa.y, acc[1]);
            acc[2] = fmaf(xe, wa.z, acc[2]); acc[3] = fmaf(xe, wa.w, acc[3]);
            acc[4] = fmaf(xe, wb.x, acc[4]); acc[5] = fmaf(xe, wb.y, acc[5]);
            acc[6] = fmaf(xe, wb.z, acc[6]); acc[7] = fmaf(xe, wb.w, acc[7]);
        }
    }

    int p0 = (i << 6) + j0;
    float* ob = out + ((size_t)b << 18) + p0 + pl2;
    #pragma unroll
    for (int k = 0; k < 8; ++k) ob[(size_t)((cg << 3) + k) << 12] = acc[k];
}

extern "C" void kernel_launch(void* const* d_in, const int* in_sizes, int n_in,
                              void* d_out, int out_size, void* d_ws, size_t ws_size,
                              hipStream_t stream) {
    const float* x    = (const float*)d_in[0];
    const float* WQw  = (const float*)d_in[1];
    const float* WQb  = (const float*)d_in[2];
    const float* WKw  = (const float*)d_in[3];
    const float* WKb  = (const float*)d_in[4];
    const float* WVw  = (const float*)d_in[5];
    const float* WVb  = (const float*)d_in[6];
    const float* WOw  = (const float*)d_in[7];
    const float* WOb  = (const float*)d_in[8];
    const float* pw1  = (const float*)d_in[9];
    const float* pb1  = (const float*)d_in[10];
    const float* pw2  = (const float*)d_in[11];
    const float* pb2  = (const float*)d_in[12];

    float* ws = (float*)d_ws;
    float* PT = ws + OFF_PT;
    float* PB = ws + OFF_PB;
    float* Qb = ws + OFF_Q;
    float* Kb = ws + OFF_K;
    float* Vb = ws + OFF_V;

    pos_qkv_kernel<<<256, 256, 0, stream>>>(
        x, WQw, WQb, WKw, WKb, WVw, WVb, pw1, pb1, pw2, pb2,
        Qb, Kb, Vb, PT, PB);
    attn_fused_kernel<<<512, 256, 0, stream>>>(
        Qb, Kb, Vb, PT, PB, WOw, WOb, (float*)d_out);
}

// Round 7
// 53.197 us; speedup vs baseline: 1.0755x; 1.0755x over previous
//
#include <hip/hip_runtime.h>
#include <hip/hip_bf16.h>
#include <math.h>

#define NPIX   4096
#define STEPF  (6.0f/63.0f)
#define SCALE  0.35355339059327373f  // 1/sqrt(8)

#define OFF_PT 0
#define OFF_PB 4096
#define OFF_Q  65536
#define OFF_K  (OFF_Q + 1048576)
#define OFF_V  (OFF_K + 1048576)

// ---------------------------------------------------------------------------
// K_A: merged positional-FFN + Q/K/V projection, 448 blocks (~2/CU for TLP).
//  blocks [0,384): qkv — 128 px-blocks x 3 matrices, 2 px/thread
//  blocks [384,448): pos FFN -> PT[49][8], PB[4096][8]; 65 entries/block
// ---------------------------------------------------------------------------
__global__ __launch_bounds__(256, 2) void pos_qkv_kernel(
    const float* __restrict__ x,
    const float* __restrict__ wq, const float* __restrict__ bq,
    const float* __restrict__ wk, const float* __restrict__ bk,
    const float* __restrict__ wv, const float* __restrict__ bv,
    const float* __restrict__ pw1, const float* __restrict__ pb1,
    const float* __restrict__ pw2, const float* __restrict__ pb2,
    float* __restrict__ Qo, float* __restrict__ Ko, float* __restrict__ Vo,
    float* __restrict__ PT, float* __restrict__ PB)
{
    __shared__ __align__(16) float smem[5632];
    int tid = threadIdx.x;
    int bid = blockIdx.x;

    if (bid < 384) {
        // ---------------- QKV projection: 128 px per block, 2 px/thread ----
        int mat = bid >> 7;          // 128 px-blocks per matrix
        const float* W; const float* bias; float* out;
        if (mat == 0)      { W = wq; bias = bq; out = Qo; }
        else if (mat == 1) { W = wk; bias = bk; out = Ko; }
        else               { W = wv; bias = bv; out = Vo; }

        float* s_W = smem;
        float* s_b = smem + 4096;
        {
            const float4* W4 = (const float4*)W;
            float4* s4 = (float4*)s_W;
            #pragma unroll
            for (int q = 0; q < 4; ++q) s4[tid + q * 256] = W4[tid + q * 256];
        }
        if (tid < 64) s_b[tid] = bias[tid];
        __syncthreads();

        int jg = tid & 3;            // 16-col output group
        int pl = tid >> 2;           // 0..63 -> 2 consecutive pixels each
        int pxblk = bid & 127;
        int g0 = pxblk << 7;         // 128 px per block, never straddles batch
        int b  = g0 >> 12;
        int pp = g0 & 4095;
        const float* xb = x + ((size_t)b << 18) + pp + (pl << 1);

        float accA[16], accB[16];
        #pragma unroll
        for (int jj = 0; jj < 16; ++jj) {
            float bv_ = s_b[(jg << 4) + jj];
            accA[jj] = bv_; accB[jj] = bv_;
        }

        #pragma unroll 4
        for (int c = 0; c < 64; ++c) {
            float2 xv = *(const float2*)(xb + ((size_t)c << 12));
            const float* wr = &s_W[(c << 6) + (jg << 4)];
            const float4 w0 = *(const float4*)(wr + 0);
            const float4 w1v = *(const float4*)(wr + 4);
            const float4 w2v = *(const float4*)(wr + 8);
            const float4 w3v = *(const float4*)(wr + 12);
            float xa = xv.x, xc = xv.y;
            accA[0]  = fmaf(xa, w0.x,  accA[0]);  accB[0]  = fmaf(xc, w0.x,  accB[0]);
            accA[1]  = fmaf(xa, w0.y,  accA[1]);  accB[1]  = fmaf(xc, w0.y,  accB[1]);
            accA[2]  = fmaf(xa, w0.z,  accA[2]);  accB[2]  = fmaf(xc, w0.z,  accB[2]);
            accA[3]  = fmaf(xa, w0.w,  accA[3]);  accB[3]  = fmaf(xc, w0.w,  accB[3]);
            accA[4]  = fmaf(xa, w1v.x, accA[4]);  accB[4]  = fmaf(xc, w1v.x, accB[4]);
            accA[5]  = fmaf(xa, w1v.y, accA[5]);  accB[5]  = fmaf(xc, w1v.y, accB[5]);
            accA[6]  = fmaf(xa, w1v.z, accA[6]);  accB[6]  = fmaf(xc, w1v.z, accB[6]);
            accA[7]  = fmaf(xa, w1v.w, accA[7]);  accB[7]  = fmaf(xc, w1v.w, accB[7]);
            accA[8]  = fmaf(xa, w2v.x, accA[8]);  accB[8]  = fmaf(xc, w2v.x, accB[8]);
            accA[9]  = fmaf(xa, w2v.y, accA[9]);  accB[9]  = fmaf(xc, w2v.y, accB[9]);
            accA[10] = fmaf(xa, w2v.z, accA[10]); accB[10] = fmaf(xc, w2v.z, accB[10]);
            accA[11] = fmaf(xa, w2v.w, accA[11]); accB[11] = fmaf(xc, w2v.w, accB[11]);
            accA[12] = fmaf(xa, w3v.x, accA[12]); accB[12] = fmaf(xc, w3v.x, accB[12]);
            accA[13] = fmaf(xa, w3v.y, accA[13]); accB[13] = fmaf(xc, w3v.y, accB[13]);
            accA[14] = fmaf(xa, w3v.z, accA[14]); accB[14] = fmaf(xc, w3v.z, accB[14]);
            accA[15] = fmaf(xa, w3v.w, accA[15]); accB[15] = fmaf(xc, w3v.w, accB[15]);
        }

        float* opA = out + (size_t)(g0 + (pl << 1)) * 64 + (jg << 4);
        float* opB = opA + 64;
        *(float4*)(opA + 0)  = make_float4(accA[0],  accA[1],  accA[2],  accA[3]);
        *(float4*)(opA + 4)  = make_float4(accA[4],  accA[5],  accA[6],  accA[7]);
        *(float4*)(opA + 8)  = make_float4(accA[8],  accA[9],  accA[10], accA[11]);
        *(float4*)(opA + 12) = make_float4(accA[12], accA[13], accA[14], accA[15]);
        *(float4*)(opB + 0)  = make_float4(accB[0],  accB[1],  accB[2],  accB[3]);
        *(float4*)(opB + 4)  = make_float4(accB[4],  accB[5],  accB[6],  accB[7]);
        *(float4*)(opB + 8)  = make_float4(accB[8],  accB[9],  accB[10], accB[11]);
        *(float4*)(opB + 12) = make_float4(accB[12], accB[13], accB[14], accB[15]);
    } else {
        // ---------------- positional FFN ----------------
        float* s_w1 = smem;          // 1024
        float* s_b1 = smem + 1024;   // 512
        float* s_w2 = smem + 1536;   // 4096
        {
            float4* s4 = (float4*)smem;
            s4[tid] = ((const float4*)pw1)[tid];
            if (tid < 128) ((float4*)s_b1)[tid] = ((const float4*)pb1)[tid];
            float4* w24 = (float4*)s_w2;
            #pragma unroll
            for (int q = 0; q < 4; ++q) w24[tid + q * 256] = ((const float4*)pw2)[tid + q * 256];
        }
        __syncthreads();

        int base = (bid - 384) * 65;           // 65 entries per block
        int lg = tid & 7;
        for (int el = tid >> 3; el < 65; el += 32) {
            int e = base + el;
            if (e >= 49 + NPIX) break;

            float r0, r1;
            if (e < 49) {
                int di = e / 7, dj = e % 7;
                r0 = (float)(di - 3) * STEPF;
                r1 = (float)(dj - 3) * STEPF;
            } else {
                int pq = e - 49;
                r0 = 3.0f - (float)(pq >> 6) * STEPF;
                r1 = 3.0f - (float)(pq & 63) * STEPF;
            }

            float acc[8] = {0.f,0.f,0.f,0.f,0.f,0.f,0.f,0.f};
            #pragma unroll 8
            for (int kk = 0; kk < 64; ++kk) {
                int k = (kk << 3) + lg;
                float hv = fmaf(r0, s_w1[k], fmaf(r1, s_w1[512 + k], s_b1[k]));
                hv = fmaxf(hv, 0.0f);
                const float4 wa = *(const float4*)&s_w2[k * 8];
                const float4 wb = *(const float4*)&s_w2[k * 8 + 4];
                acc[0] = fmaf(hv, wa.x, acc[0]);
                acc[1] = fmaf(hv, wa.y, acc[1]);
                acc[2] = fmaf(hv, wa.z, acc[2]);
                acc[3] = fmaf(hv, wa.w, acc[3]);
                acc[4] = fmaf(hv, wb.x, acc[4]);
                acc[5] = fmaf(hv, wb.y, acc[5]);
                acc[6] = fmaf(hv, wb.z, acc[6]);
                acc[7] = fmaf(hv, wb.w, acc[7]);
            }
            #pragma unroll
            for (int m = 1; m < 8; m <<= 1) {
                #pragma unroll
                for (int jx = 0; jx < 8; ++jx) acc[jx] += __shfl_xor(acc[jx], m);
            }
            float v = acc[lg] + pb2[lg];
            if (e < 49) PT[e * 8 + lg] = v;
            else        PB[(e - 49) * 8 + lg] = v;
        }
    }
}

// ---------------------------------------------------------------------------
// K_B: neighborhood attention, LDS-staged K/V halo, fused output projection.
// Block = 32-px row chunk x 8 heads (256 thr). LDS: KV tile [7][38][68]
// reused for K then V; PT in VGPRs; WO read from global (broadcast, L1-hot).
// 4 barriers; 81,312 B LDS -> 2 blocks/CU.
// ---------------------------------------------------------------------------
__global__ __launch_bounds__(256, 2) void attn_fused_kernel(
    const float* __restrict__ Q, const float* __restrict__ K,
    const float* __restrict__ V, const float* __restrict__ PT,
    const float* __restrict__ PB, const float* __restrict__ WO,
    const float* __restrict__ bO, float* __restrict__ out)
{
    __shared__ __align__(16) float s_KV[7 * 38 * 68];   // 72,352 B
    __shared__ __align__(16) float s_O[32 * 68];        //  8,704 B
    __shared__ float s_bias[64];

    int tid  = threadIdx.x;
    int bid  = blockIdx.x;
    int b    = bid >> 7;            // 128 blocks per batch
    int pblk = bid & 127;
    int i    = pblk >> 1;
    int j0   = (pblk & 1) << 5;
    int h    = tid & 7;
    int pxl  = tid >> 3;            // 0..31
    int j    = j0 + pxl;
    int p    = (i << 6) + j;

    if (tid < 64) s_bias[tid] = bO[tid];

    // positional tables -> registers
    float pt[49];
    #pragma unroll
    for (int r = 0; r < 49; ++r) pt[r] = PT[(r << 3) + h];
    float pbv = PB[(p << 3) + h];

    const float* qp = Q + ((size_t)((b << 12) + p) << 6) + (h << 3);
    const float4 qa = *(const float4*)qp;
    const float4 qb = *(const float4*)(qp + 4);

    const float* Kb = K + ((size_t)b << 18);
    const float* Vb = V + ((size_t)b << 18);

    // ---- stage K halo: rows i-3..i+3 (clamped), cols j0-3..j0+34 (clamped) ----
    #pragma unroll
    for (int r = 0; r < 7; ++r) {
        int ic = i - 3 + r; ic = ic < 0 ? 0 : (ic > 63 ? 63 : ic);
        const float* rowb = Kb + ((size_t)ic << 12);
        for (int v = tid; v < 608; v += 256) {        // 38 cols * 16 float4
            int cc = v >> 4, q4 = v & 15;
            int jc = j0 - 3 + cc; jc = jc < 0 ? 0 : (jc > 63 ? 63 : jc);
            *(float4*)&s_KV[(r * 38 + cc) * 68 + (q4 << 2)] =
                *(const float4*)(rowb + (jc << 6) + (q4 << 2));
        }
    }
    __syncthreads();

    // ---- score pass ----
    float sc[49];
    float mx = -1e30f;
    #pragma unroll
    for (int di = 0; di < 7; ++di) {
        int i2 = i + di - 3;
        bool iok = (unsigned)i2 < 64u;
        const float* krow = &s_KV[(di * 38 + pxl) * 68 + (h << 3)];
        #pragma unroll
        for (int dj = 0; dj < 7; ++dj) {
            int j2 = j + dj - 3;
            bool ok = iok && ((unsigned)j2 < 64u);
            const float* kp = krow + dj * 68;
            const float4 ka  = *(const float4*)kp;
            const float4 kb2 = *(const float4*)(kp + 4);
            float da = fmaf(qa.y, ka.y, qa.x * ka.x);
            da = fmaf(qa.w, ka.w, fmaf(qa.z, ka.z, da));
            float db = fmaf(qb.y, kb2.y, qb.x * kb2.x);
            db = fmaf(qb.w, kb2.w, fmaf(qb.z, kb2.z, db));
            int r = di * 7 + dj;
            float s = fmaf(da + db, SCALE, pt[r]);
            s = ok ? s : pbv;
            sc[r] = s;
            mx = fmaxf(mx, s);
        }
    }
    __syncthreads();   // all K reads complete before overwrite

    // ---- stage V halo into the same buffer ----
    #pragma unroll
    for (int r = 0; r < 7; ++r) {
        int ic = i - 3 + r; ic = ic < 0 ? 0 : (ic > 63 ? 63 : ic);
        const float* rowb = Vb + ((size_t)ic << 12);
        for (int v = tid; v < 608; v += 256) {
            int cc = v >> 4, q4 = v & 15;
            int jc = j0 - 3 + cc; jc = jc < 0 ? 0 : (jc > 63 ? 63 : jc);
            *(float4*)&s_KV[(r * 38 + cc) * 68 + (q4 << 2)] =
                *(const float4*)(rowb + (jc << 6) + (q4 << 2));
        }
    }
    __syncthreads();

    // ---- softmax + PV ----
    float sum = 0.0f;
    float o0=0.f,o1=0.f,o2=0.f,o3=0.f,o4=0.f,o5=0.f,o6=0.f,o7=0.f;
    #pragma unroll
    for (int di = 0; di < 7; ++di) {
        int i2 = i + di - 3;
        bool iok = (unsigned)i2 < 64u;
        const float* vrow = &s_KV[(di * 38 + pxl) * 68 + (h << 3)];
        #pragma unroll
        for (int dj = 0; dj < 7; ++dj) {
            int j2 = j + dj - 3;
            bool ok = iok && ((unsigned)j2 < 64u);
            int r = di * 7 + dj;
            float e = __expf(sc[r] - mx);
            sum += e;
            float ew = ok ? e : 0.0f;
            const float* vp = vrow + dj * 68;
            const float4 va  = *(const float4*)vp;
            const float4 vb2 = *(const float4*)(vp + 4);
            o0 = fmaf(ew, va.x, o0); o1 = fmaf(ew, va.y, o1);
            o2 = fmaf(ew, va.z, o2); o3 = fmaf(ew, va.w, o3);
            o4 = fmaf(ew, vb2.x, o4); o5 = fmaf(ew, vb2.y, o5);
            o6 = fmaf(ew, vb2.z, o6); o7 = fmaf(ew, vb2.w, o7);
        }
    }
    float inv = 1.0f / sum;
    {
        float* so = &s_O[pxl * 68 + (h << 3)];
        *(float4*)(so + 0) = make_float4(o0 * inv, o1 * inv, o2 * inv, o3 * inv);
        *(float4*)(so + 4) = make_float4(o4 * inv, o5 * inv, o6 * inv, o7 * inv);
    }
    __syncthreads();   // s_O complete

    // ---- epilogue: out[b, ch, p] = bias[ch] + sum_c s_O[p][c] * WO[c][ch]
    //      WO read directly from global: uniform per cg-group -> 1 line/instr,
    //      L1-resident after first touch.
    int pl2 = tid & 31;
    int cg  = tid >> 5;           // 8 output channels per thread
    float acc[8];
    #pragma unroll
    for (int k = 0; k < 8; ++k) acc[k] = s_bias[(cg << 3) + k];

    #pragma unroll 4
    for (int c4 = 0; c4 < 16; ++c4) {
        float4 xv = *(const float4*)&s_O[pl2 * 68 + (c4 << 2)];
        float xs[4] = {xv.x, xv.y, xv.z, xv.w};
        #pragma unroll
        for (int e = 0; e < 4; ++e) {
            int c = (c4 << 2) + e;
            const float* wr = WO + (c << 6) + (cg << 3);
            const float4 wa = *(const float4*)wr;
            const float4 wb = *(const float4*)(wr + 4);
            float xe = xs[e];
            acc[0] = fmaf(xe, wa.x, acc[0]); acc[1] = fmaf(xe, wa.y, acc[1]);
            acc[2] = fmaf(xe, wa.z, acc[2]); acc[3] = fmaf(xe, wa.w, acc[3]);
            acc[4] = fmaf(xe, wb.x, acc[4]); acc[5] = fmaf(xe, wb.y, acc[5]);
            acc[6] = fmaf(xe, wb.z, acc[6]); acc[7] = fmaf(xe, wb.w, acc[7]);
        }
    }

    int p0 = (i << 6) + j0;
    float* ob = out + ((size_t)b << 18) + p0 + pl2;
    #pragma unroll
    for (int k = 0; k < 8; ++k) ob[(size_t)((cg << 3) + k) << 12] = acc[k];
}

extern "C" void kernel_launch(void* const* d_in, const int* in_sizes, int n_in,
                              void* d_out, int out_size, void* d_ws, size_t ws_size,
                              hipStream_t stream) {
    const float* x    = (const float*)d_in[0];
    const float* WQw  = (const float*)d_in[1];
    const float* WQb  = (const float*)d_in[2];
    const float* WKw  = (const float*)d_in[3];
    const float* WKb  = (const float*)d_in[4];
    const float* WVw  = (const float*)d_in[5];
    const float* WVb  = (const float*)d_in[6];
    const float* WOw  = (const float*)d_in[7];
    const float* WOb  = (const float*)d_in[8];
    const float* pw1  = (const float*)d_in[9];
    const float* pb1  = (const float*)d_in[10];
    const float* pw2  = (const float*)d_in[11];
    const float* pb2  = (const float*)d_in[12];

    float* ws = (float*)d_ws;
    float* PT = ws + OFF_PT;
    float* PB = ws + OFF_PB;
    float* Qb = ws + OFF_Q;
    float* Kb = ws + OFF_K;
    float* Vb = ws + OFF_V;

    pos_qkv_kernel<<<448, 256, 0, stream>>>(
        x, WQw, WQb, WKw, WKb, WVw, WVb, pw1, pb1, pw2, pb2,
        Qb, Kb, Vb, PT, PB);
    attn_fused_kernel<<<512, 256, 0, stream>>>(
        Qb, Kb, Vb, PT, PB, WOw, WOb, (float*)d_out);
}